// Round 5
// baseline (304.591 us; speedup 1.0000x reference)
//
#include <hip/hip_runtime.h>

#define IN_DIM  2048   // K
#define OUT_DIM 2048   // N
#define MROWS   8192   // M = B*S
#define RANK    4

typedef unsigned short ushort_t;
typedef __attribute__((ext_vector_type(8))) short  short8;   // 8 bf16 (4 VGPRs)
typedef __attribute__((ext_vector_type(4))) float  floatx4;  // MFMA acc

__device__ __forceinline__ unsigned short f2bf(float f) {
  union { float f; unsigned int u; } v; v.f = f;
  unsigned int r = v.u + 0x7fffu + ((v.u >> 16) & 1u);  // RNE
  return (unsigned short)(r >> 16);
}

__device__ __forceinline__ void gload16(const ushort_t* g, short* l) {
  __builtin_amdgcn_global_load_lds(
      (const __attribute__((address_space(1))) void*)g,
      (__attribute__((address_space(3))) void*)l, 16, 0, 0);
}

// ---- kernel 1 (fused prep): blocks [0,8192): cast x->bf16
//      blocks [8192,10240): rank coeffs (wave-shuffle reduce) + build W row ----
__global__ void prep_kernel(const float* __restrict__ x, ushort_t* __restrict__ xb,
                            const int* __restrict__ idx, const float* __restrict__ lut,
                            const float* __restrict__ sA, const float* __restrict__ sB,
                            const float* __restrict__ mag, ushort_t* __restrict__ W) {
  int t = threadIdx.x;
  if (blockIdx.x < 8192) {
    size_t i = ((size_t)blockIdx.x * 256 + t) * 8;
    float4 a = *(const float4*)(x + i);
    float4 b = *(const float4*)(x + i + 4);
    uint4 o4;
    o4.x = (unsigned)f2bf(a.x) | ((unsigned)f2bf(a.y) << 16);
    o4.y = (unsigned)f2bf(a.z) | ((unsigned)f2bf(a.w) << 16);
    o4.z = (unsigned)f2bf(b.x) | ((unsigned)f2bf(b.y) << 16);
    o4.w = (unsigned)f2bf(b.z) | ((unsigned)f2bf(b.w) << 16);
    *(uint4*)(xb + i) = o4;
  } else {
    __shared__ float red[8][4];
    __shared__ float tot[8];
    __shared__ float aA[4];       // |A[o,r]| * c[r]
    __shared__ float lutS[16];
    int o = blockIdx.x - 8192;
    int lane = t & 63, wid = t >> 6;
    float v[8] = {0.f, 0.f, 0.f, 0.f, 0.f, 0.f, 0.f, 0.f};
    for (int oo = t; oo < OUT_DIM; oo += 256) {
      float4 a = *(const float4*)(sA + oo * 4);
      v[0] += a.x * a.x; v[1] += a.y * a.y; v[2] += a.z * a.z; v[3] += a.w * a.w;
    }
    for (int r = 0; r < 4; ++r)
      for (int i = t; i < IN_DIM; i += 256) { float b = sB[r * IN_DIM + i]; v[4 + r] += b * b; }
    for (int d = 1; d < 64; d <<= 1)
      #pragma unroll
      for (int q = 0; q < 8; ++q) v[q] += __shfl_xor(v[q], d, 64);
    if (lane == 0)
      #pragma unroll
      for (int q = 0; q < 8; ++q) red[q][wid] = v[q];
    __syncthreads();
    if (t < 8) tot[t] = red[t][0] + red[t][1] + red[t][2] + red[t][3];
    if (t < 16) lutS[t] = lut[t];
    __syncthreads();
    if (t < 4) {
      float g  = log1pf(expf(mag[t])) + 1e-6f;        // softplus + mag_eps
      float na = fmaxf(sqrtf(tot[t]),     1e-6f);
      float nb = fmaxf(sqrtf(tot[4 + t]), 1e-6f);
      aA[t] = (g / (na * nb)) * fabsf(sA[o * 4 + t]);
    }
    __syncthreads();
    int i = t * 8;
    const int4* ip4 = (const int4*)(idx + (size_t)o * IN_DIM + i);
    int4 i0 = ip4[0], i1 = ip4[1];
    int ii[8] = {i0.x, i0.y, i0.z, i0.w, i1.x, i1.y, i1.z, i1.w};
    unsigned short u[8];
    #pragma unroll
    for (int j = 0; j < 8; ++j) {
      float s = aA[0] * fabsf(sB[0 * IN_DIM + i + j])
              + aA[1] * fabsf(sB[1 * IN_DIM + i + j])
              + aA[2] * fabsf(sB[2 * IN_DIM + i + j])
              + aA[3] * fabsf(sB[3 * IN_DIM + i + j]);
      u[j] = f2bf(lutS[ii[j]] * s);
    }
    uint4 o4;
    o4.x = (unsigned)u[0] | ((unsigned)u[1] << 16);
    o4.y = (unsigned)u[2] | ((unsigned)u[3] << 16);
    o4.z = (unsigned)u[4] | ((unsigned)u[5] << 16);
    o4.w = (unsigned)u[6] | ((unsigned)u[7] << 16);
    *(uint4*)(W + (size_t)o * IN_DIM + i) = o4;
  }
}

// ---- kernel 2: C[M,N] = A[M,K] * W[N,K]^T + bias ----
// Block tile 256x128, 4 waves (2x2), wave tile 128x64 -> 384 B LDS per MFMA
// (vs 512 at 64x64): lifts the LDS-read-BW ceiling from ~30% to ~40% MfmaUtil.
// XOR swizzle (R2-verified, conflicts=0): chunk j at byte j*16; row=j>>2, slot=j&3;
// slot c of row r holds k-chunk c ^ ((r>>1)&3).
__global__ __launch_bounds__(256) void gemm_kernel(const ushort_t* __restrict__ A,
                                                   const ushort_t* __restrict__ W,
                                                   const float* __restrict__ bias,
                                                   float* __restrict__ C) {
  __shared__ short As[256 * 32];   // 16 KB
  __shared__ short Bs[128 * 32];   // 8 KB
  const int t    = threadIdx.x;
  const int lane = t & 63;
  const int wid  = t >> 6;
  const int wr   = wid >> 1;   // wave row 0/1 -> M rows wr*128..wr*128+127
  const int wc   = wid & 1;    // wave col 0/1 -> N cols wc*64..wc*64+63
  const int rowBase = blockIdx.y * 256;
  const int colBase = blockIdx.x * 128;

  floatx4 acc[8][4];
  #pragma unroll
  for (int i = 0; i < 8; ++i)
    #pragma unroll
    for (int j = 0; j < 4; ++j) acc[i][j] = (floatx4){0.f, 0.f, 0.f, 0.f};

  // staging: A = 1024 chunks (4 rounds), B = 512 chunks (2 rounds)
  const int row0 = t >> 2;
  const int c0   = t & 3;
  const int kc0  = c0 ^ ((row0 >> 1) & 3);   // XOR swizzle (row+64q keeps (row>>1)&3)
  const ushort_t* ag[4]; const ushort_t* bg[2];
  short* al[4]; short* bl[2];
  #pragma unroll
  for (int q = 0; q < 4; ++q) {
    ag[q] = A + (size_t)(rowBase + row0 + q * 64) * IN_DIM + kc0 * 8;
    al[q] = As + ((q * 256 + wid * 64)) * 8;       // wave-uniform LDS bases
  }
  #pragma unroll
  for (int q = 0; q < 2; ++q) {
    bg[q] = W + (size_t)(colBase + row0 + q * 64) * IN_DIM + kc0 * 8;
    bl[q] = Bs + ((q * 256 + wid * 64)) * 8;
  }

  const int rA   = lane & 15;                       // row within 16x16 tile
  const int slot = ((rA >> 1) & 3) ^ (lane >> 4);   // swizzled k-slot
  const int kOff = slot * 8;

  for (int k0 = 0; k0 < IN_DIM; k0 += 32) {
    #pragma unroll
    for (int q = 0; q < 4; ++q) gload16(ag[q] + k0, al[q]);
    #pragma unroll
    for (int q = 0; q < 2; ++q) gload16(bg[q] + k0, bl[q]);
    __syncthreads();

    short8 af[8], bf[4];
    #pragma unroll
    for (int mi = 0; mi < 8; ++mi)
      af[mi] = *(const short8*)(As + (wr * 128 + mi * 16 + rA) * 32 + kOff);
    #pragma unroll
    for (int ni = 0; ni < 4; ++ni)
      bf[ni] = *(const short8*)(Bs + (wc * 64 + ni * 16 + rA) * 32 + kOff);
    #pragma unroll
    for (int mi = 0; mi < 8; ++mi)
      #pragma unroll
      for (int ni = 0; ni < 4; ++ni)
        acc[mi][ni] = __builtin_amdgcn_mfma_f32_16x16x32_bf16(af[mi], bf[ni], acc[mi][ni], 0, 0, 0);
    __syncthreads();
  }

  // epilogue: D col = lane&15, row = (lane>>4)*4 + reg
  const int mB = rowBase + wr * 128 + (lane >> 4) * 4;
  const int nB = colBase + wc * 64 + (lane & 15);
  #pragma unroll
  for (int ni = 0; ni < 4; ++ni) {
    float bv = bias[nB + ni * 16];
    #pragma unroll
    for (int mi = 0; mi < 8; ++mi)
      #pragma unroll
      for (int r = 0; r < 4; ++r)
        C[(size_t)(mB + mi * 16 + r) * OUT_DIM + (nB + ni * 16)] = acc[mi][ni][r] + bv;
  }
}

extern "C" void kernel_launch(void* const* d_in, const int* in_sizes, int n_in,
                              void* d_out, int out_size, void* d_ws, size_t ws_size,
                              hipStream_t stream) {
  const float* x    = (const float*)d_in[0];
  const int*   idx  = (const int*)d_in[1];
  const float* lut  = (const float*)d_in[2];
  const float* sA   = (const float*)d_in[3];
  const float* sB   = (const float*)d_in[4];
  const float* mag  = (const float*)d_in[5];
  const float* bias = (const float*)d_in[6];
  float* y = (float*)d_out;

  char* ws = (char*)d_ws;
  ushort_t* W  = (ushort_t*)ws;                                   // 8 MiB
  ushort_t* xb = (ushort_t*)(ws + (size_t)OUT_DIM * IN_DIM * 2);  // 32 MiB

  prep_kernel<<<8192 + OUT_DIM, 256, 0, stream>>>(x, xb, idx, lut, sA, sB, mag, W);
  dim3 g(OUT_DIM / 128, MROWS / 256);
  gemm_kernel<<<g, 256, 0, stream>>>(xb, W, bias, y);
}

// Round 6
// 251.674 us; speedup vs baseline: 1.2103x; 1.2103x over previous
//
#include <hip/hip_runtime.h>

#define IN_DIM  2048   // K
#define OUT_DIM 2048   // N
#define MROWS   8192   // M = B*S
#define RANK    4

typedef unsigned short ushort_t;
typedef __attribute__((ext_vector_type(8))) short  short8;   // 8 bf16 (4 VGPRs)
typedef __attribute__((ext_vector_type(4))) float  floatx4;  // MFMA acc

__device__ __forceinline__ unsigned short f2bf(float f) {
  union { float f; unsigned int u; } v; v.f = f;
  unsigned int r = v.u + 0x7fffu + ((v.u >> 16) & 1u);  // RNE
  return (unsigned short)(r >> 16);
}

// ---- kernel 1 (fused prep): blocks [0,8192): cast x->bf16
//      blocks [8192,10240): rank coeffs (wave-shuffle reduce) + build W row ----
__global__ void prep_kernel(const float* __restrict__ x, ushort_t* __restrict__ xb,
                            const int* __restrict__ idx, const float* __restrict__ lut,
                            const float* __restrict__ sA, const float* __restrict__ sB,
                            const float* __restrict__ mag, ushort_t* __restrict__ W) {
  int t = threadIdx.x;
  if (blockIdx.x < 8192) {
    size_t i = ((size_t)blockIdx.x * 256 + t) * 8;
    float4 a = *(const float4*)(x + i);
    float4 b = *(const float4*)(x + i + 4);
    uint4 o4;
    o4.x = (unsigned)f2bf(a.x) | ((unsigned)f2bf(a.y) << 16);
    o4.y = (unsigned)f2bf(a.z) | ((unsigned)f2bf(a.w) << 16);
    o4.z = (unsigned)f2bf(b.x) | ((unsigned)f2bf(b.y) << 16);
    o4.w = (unsigned)f2bf(b.z) | ((unsigned)f2bf(b.w) << 16);
    *(uint4*)(xb + i) = o4;
  } else {
    __shared__ float red[8][4];
    __shared__ float tot[8];
    __shared__ float aA[4];       // |A[o,r]| * c[r]
    __shared__ float lutS[16];
    int o = blockIdx.x - 8192;
    int lane = t & 63, wid = t >> 6;
    float v[8] = {0.f, 0.f, 0.f, 0.f, 0.f, 0.f, 0.f, 0.f};
    for (int oo = t; oo < OUT_DIM; oo += 256) {
      float4 a = *(const float4*)(sA + oo * 4);
      v[0] += a.x * a.x; v[1] += a.y * a.y; v[2] += a.z * a.z; v[3] += a.w * a.w;
    }
    for (int r = 0; r < 4; ++r)
      for (int i = t; i < IN_DIM; i += 256) { float b = sB[r * IN_DIM + i]; v[4 + r] += b * b; }
    for (int d = 1; d < 64; d <<= 1)
      #pragma unroll
      for (int q = 0; q < 8; ++q) v[q] += __shfl_xor(v[q], d, 64);
    if (lane == 0)
      #pragma unroll
      for (int q = 0; q < 8; ++q) red[q][wid] = v[q];
    __syncthreads();
    if (t < 8) tot[t] = red[t][0] + red[t][1] + red[t][2] + red[t][3];
    if (t < 16) lutS[t] = lut[t];
    __syncthreads();
    if (t < 4) {
      float g  = log1pf(expf(mag[t])) + 1e-6f;        // softplus + mag_eps
      float na = fmaxf(sqrtf(tot[t]),     1e-6f);
      float nb = fmaxf(sqrtf(tot[4 + t]), 1e-6f);
      aA[t] = (g / (na * nb)) * fabsf(sA[o * 4 + t]);
    }
    __syncthreads();
    int i = t * 8;
    const int4* ip4 = (const int4*)(idx + (size_t)o * IN_DIM + i);
    int4 i0 = ip4[0], i1 = ip4[1];
    int ii[8] = {i0.x, i0.y, i0.z, i0.w, i1.x, i1.y, i1.z, i1.w};
    unsigned short u[8];
    #pragma unroll
    for (int j = 0; j < 8; ++j) {
      float s = aA[0] * fabsf(sB[0 * IN_DIM + i + j])
              + aA[1] * fabsf(sB[1 * IN_DIM + i + j])
              + aA[2] * fabsf(sB[2 * IN_DIM + i + j])
              + aA[3] * fabsf(sB[3 * IN_DIM + i + j]);
      u[j] = f2bf(lutS[ii[j]] * s);
    }
    uint4 o4;
    o4.x = (unsigned)u[0] | ((unsigned)u[1] << 16);
    o4.y = (unsigned)u[2] | ((unsigned)u[3] << 16);
    o4.z = (unsigned)u[4] | ((unsigned)u[5] << 16);
    o4.w = (unsigned)u[6] | ((unsigned)u[7] << 16);
    *(uint4*)(W + (size_t)o * IN_DIM + i) = o4;
  }
}

// ---- kernel 2: C[M,N] = A[M,K] * W[N,K]^T + bias ----
// Register-staged pipeline (Tensile-style): buffer_load -> VGPR -> ds_write ->
// double-buffered LDS -> MFMA. One barrier per k-iter; the barrier drains only
// lgkmcnt (ds ops) — global loads to VGPRs stay in flight across it, so the
// next tile's loads overlap the current tile's MFMAs.
// R2 geometry: 128x128 block, 4 waves 2x2, wave tile 64x64, BK=32.
// XOR swizzle (R2-verified, conflicts=0): chunk j at byte j*16; row=j>>2, slot=j&3;
// slot c of row r holds k-chunk c ^ ((r>>1)&3).
__global__ __launch_bounds__(256) void gemm_kernel(const ushort_t* __restrict__ A,
                                                   const ushort_t* __restrict__ W,
                                                   const float* __restrict__ bias,
                                                   float* __restrict__ C) {
  __shared__ short As[2][128 * 32];   // 2 x 8 KB
  __shared__ short Bs[2][128 * 32];   // 2 x 8 KB
  const int t    = threadIdx.x;
  const int lane = t & 63;
  const int wid  = t >> 6;
  const int wr   = wid >> 1;   // 2x2 wave grid, each wave owns 64x64
  const int wc   = wid & 1;
  const int rowBase = blockIdx.y * 128;
  const int colBase = blockIdx.x * 128;

  floatx4 acc[4][4];
  #pragma unroll
  for (int i = 0; i < 4; ++i)
    #pragma unroll
    for (int j = 0; j < 4; ++j) acc[i][j] = (floatx4){0.f, 0.f, 0.f, 0.f};

  // global staging addresses (R2 pattern): thread t covers chunk j0=t, j1=t+256
  const int row0 = t >> 2;
  const int c0   = t & 3;
  const int kc0  = c0 ^ ((row0 >> 1) & 3);   // XOR swizzle
  const ushort_t* a0 = A + (size_t)(rowBase + row0) * IN_DIM + kc0 * 8;
  const ushort_t* a1 = A + (size_t)(rowBase + row0 + 64) * IN_DIM + kc0 * 8;
  const ushort_t* b0 = W + (size_t)(colBase + row0) * IN_DIM + kc0 * 8;
  const ushort_t* b1 = W + (size_t)(colBase + row0 + 64) * IN_DIM + kc0 * 8;

  // LDS write targets: chunk j at elem j*8 (byte j*16) — per-lane scatter is
  // fine for ds_write (no global_load_lds constraint)
  short* wA0 = &As[0][t * 8];
  short* wA1 = &As[0][(t + 256) * 8];
  short* wB0 = &Bs[0][t * 8];
  short* wB1 = &Bs[0][(t + 256) * 8];

  const int rA   = lane & 15;                       // row within 16x16 tile
  const int slot = ((rA >> 1) & 3) ^ (lane >> 4);   // swizzled k-slot
  const int kOff = slot * 8;

  // prefetch k=0 into registers
  uint4 ra0 = *(const uint4*)a0;
  uint4 ra1 = *(const uint4*)a1;
  uint4 rb0 = *(const uint4*)b0;
  uint4 rb1 = *(const uint4*)b1;

  for (int k0 = 0; k0 < IN_DIM; k0 += 32) {
    const int buf = (k0 >> 5) & 1;
    const int off = buf * 4096;          // elems per LDS buffer (8 KB)
    // commit current registers to LDS (waits vmcnt for these regs only)
    *(uint4*)(wA0 + off) = ra0;
    *(uint4*)(wA1 + off) = ra1;
    *(uint4*)(wB0 + off) = rb0;
    *(uint4*)(wB1 + off) = rb1;
    // issue next tile's loads — these stay in flight across the barrier
    if (k0 + 32 < IN_DIM) {
      ra0 = *(const uint4*)(a0 + k0 + 32);
      ra1 = *(const uint4*)(a1 + k0 + 32);
      rb0 = *(const uint4*)(b0 + k0 + 32);
      rb1 = *(const uint4*)(b1 + k0 + 32);
    }
    __syncthreads();   // drains lgkm (ds_writes); also orders read-before-rewrite

    const short* Ab = &As[buf][0];
    const short* Bb = &Bs[buf][0];
    short8 af[4], bf[4];
    #pragma unroll
    for (int mi = 0; mi < 4; ++mi)
      af[mi] = *(const short8*)(Ab + (wr * 64 + mi * 16 + rA) * 32 + kOff);
    #pragma unroll
    for (int ni = 0; ni < 4; ++ni)
      bf[ni] = *(const short8*)(Bb + (wc * 64 + ni * 16 + rA) * 32 + kOff);
    #pragma unroll
    for (int mi = 0; mi < 4; ++mi)
      #pragma unroll
      for (int ni = 0; ni < 4; ++ni)
        acc[mi][ni] = __builtin_amdgcn_mfma_f32_16x16x32_bf16(af[mi], bf[ni], acc[mi][ni], 0, 0, 0);
    // no second barrier: double-buffered LDS; next iter writes the other buffer
  }

  // epilogue: D col = lane&15, row = (lane>>4)*4 + reg
  const int mB = rowBase + wr * 64 + (lane >> 4) * 4;
  const int nB = colBase + wc * 64 + (lane & 15);
  #pragma unroll
  for (int ni = 0; ni < 4; ++ni) {
    float bv = bias[nB + ni * 16];
    #pragma unroll
    for (int mi = 0; mi < 4; ++mi)
      #pragma unroll
      for (int r = 0; r < 4; ++r)
        C[(size_t)(mB + mi * 16 + r) * OUT_DIM + (nB + ni * 16)] = acc[mi][ni][r] + bv;
  }
}

extern "C" void kernel_launch(void* const* d_in, const int* in_sizes, int n_in,
                              void* d_out, int out_size, void* d_ws, size_t ws_size,
                              hipStream_t stream) {
  const float* x    = (const float*)d_in[0];
  const int*   idx  = (const int*)d_in[1];
  const float* lut  = (const float*)d_in[2];
  const float* sA   = (const float*)d_in[3];
  const float* sB   = (const float*)d_in[4];
  const float* mag  = (const float*)d_in[5];
  const float* bias = (const float*)d_in[6];
  float* y = (float*)d_out;

  char* ws = (char*)d_ws;
  ushort_t* W  = (ushort_t*)ws;                                   // 8 MiB
  ushort_t* xb = (ushort_t*)(ws + (size_t)OUT_DIM * IN_DIM * 2);  // 32 MiB

  prep_kernel<<<8192 + OUT_DIM, 256, 0, stream>>>(x, xb, idx, lut, sA, sB, mag, W);
  dim3 g(OUT_DIM / 128, MROWS / 128);
  gemm_kernel<<<g, 256, 0, stream>>>(xb, W, bias, y);
}